// Round 3
// baseline (156.278 us; speedup 1.0000x reference)
//
#include <hip/hip_runtime.h>

// Per-edge dot product: out[e] = dot(h[src[e]], h[dst[e]]), D=128 fp32.
// 16 lanes per edge: each lane loads 2x float4 (32B) of each row -> a full
// 512B row is one coalesced segment across the group. 2-edge unroll for MLP
// (8 independent row loads in flight) + software-pipelined index loads so
// next iteration's index fetch overlaps current row gathers. Reduction via
// 4 shfl_xor steps (all partners within the 16-lane group; branches are
// group-uniform so the group never diverges internally).

constexpr int D   = 128;
constexpr int LPE = 16;      // lanes per edge

__global__ __launch_bounds__(256) void edge_dot_kernel(
    const float* __restrict__ h,
    const int*   __restrict__ src,
    const int*   __restrict__ dst,
    float*       __restrict__ out,
    int E)
{
    const int tid    = blockIdx.x * blockDim.x + threadIdx.x;
    const int sub    = threadIdx.x & (LPE - 1);   // lane within 16-lane group
    const int slot   = tid / LPE;
    const int nslots = (gridDim.x * blockDim.x) / LPE;
    const int off    = sub * 2;                   // float4 offset within row

    int e = slot;
    // Prologue: prefetch first pair's indices.
    int s1 = 0, t1 = 0, s2 = 0, t2 = 0;
    if (e + nslots < E) {
        s1 = src[e];          t1 = dst[e];
        s2 = src[e + nslots]; t2 = dst[e + nslots];
    }

    while (e + nslots < E) {
        const int e2 = e + nslots;
        const int en = e + 2 * nslots;

        // Issue row gathers for the current pair (indices already resident).
        const float4* hu1 = reinterpret_cast<const float4*>(h + (size_t)s1 * D) + off;
        const float4* hv1 = reinterpret_cast<const float4*>(h + (size_t)t1 * D) + off;
        const float4* hu2 = reinterpret_cast<const float4*>(h + (size_t)s2 * D) + off;
        const float4* hv2 = reinterpret_cast<const float4*>(h + (size_t)t2 * D) + off;

        float4 a0 = hu1[0]; float4 a1 = hu1[1];
        float4 b0 = hv1[0]; float4 b1 = hv1[1];
        float4 c0 = hu2[0]; float4 c1 = hu2[1];
        float4 d0 = hv2[0]; float4 d1 = hv2[1];

        // Prefetch next pair's indices while row loads are in flight.
        if (en + nslots < E) {
            s1 = src[en];          t1 = dst[en];
            s2 = src[en + nslots]; t2 = dst[en + nslots];
        }

        float acc1 = a0.x * b0.x + a0.y * b0.y + a0.z * b0.z + a0.w * b0.w
                   + a1.x * b1.x + a1.y * b1.y + a1.z * b1.z + a1.w * b1.w;
        float acc2 = c0.x * d0.x + c0.y * d0.y + c0.z * d0.z + c0.w * d0.w
                   + c1.x * d1.x + c1.y * d1.y + c1.z * d1.z + c1.w * d1.w;

        acc1 += __shfl_xor(acc1, 1);
        acc1 += __shfl_xor(acc1, 2);
        acc1 += __shfl_xor(acc1, 4);
        acc1 += __shfl_xor(acc1, 8);
        acc2 += __shfl_xor(acc2, 1);
        acc2 += __shfl_xor(acc2, 2);
        acc2 += __shfl_xor(acc2, 4);
        acc2 += __shfl_xor(acc2, 8);

        if (sub == 0) {
            out[e]  = acc1;
            out[e2] = acc2;
        }
        e = en;
    }

    // Tail: at most one remaining edge per slot.
    if (e < E) {
        const int s = src[e];
        const int t = dst[e];
        const float4* hu = reinterpret_cast<const float4*>(h + (size_t)s * D) + off;
        const float4* hv = reinterpret_cast<const float4*>(h + (size_t)t * D) + off;
        float4 a0 = hu[0]; float4 a1 = hu[1];
        float4 b0 = hv[0]; float4 b1 = hv[1];
        float acc = a0.x * b0.x + a0.y * b0.y + a0.z * b0.z + a0.w * b0.w
                  + a1.x * b1.x + a1.y * b1.y + a1.z * b1.z + a1.w * b1.w;
        acc += __shfl_xor(acc, 1);
        acc += __shfl_xor(acc, 2);
        acc += __shfl_xor(acc, 4);
        acc += __shfl_xor(acc, 8);
        if (sub == 0) out[e] = acc;
    }
}

extern "C" void kernel_launch(void* const* d_in, const int* in_sizes, int n_in,
                              void* d_out, int out_size, void* d_ws, size_t ws_size,
                              hipStream_t stream) {
    const float* h   = (const float*)d_in[0];
    const int*   src = (const int*)d_in[1];
    const int*   dst = (const int*)d_in[2];
    float*       out = (float*)d_out;

    const int E = in_sizes[1];   // 600000 edges

    // 2048 blocks x 256 threads = 32 waves/CU (max occupancy) to hide
    // random-gather latency; grid-stride covers all edges.
    const int block = 256;
    const int edges_per_block = block / LPE;                 // 16
    int grid = (E + edges_per_block - 1) / edges_per_block;
    if (grid > 2048) grid = 2048;

    edge_dot_kernel<<<grid, block, 0, stream>>>(h, src, dst, out, E);
}

// Round 4
// 129.944 us; speedup vs baseline: 1.2027x; 1.2027x over previous
//
#include <hip/hip_runtime.h>
#include <hip/hip_fp16.h>

// out[e] = dot(h[src[e]], h[dst[e]]), D=128, N=100k, E=600k.
// Strategy: stage h as fp16 in d_ws (halves gather traffic: row 512B->256B,
// footprint 51->25.6MB vs 32MB aggregate L2), then 16 lanes/edge gather:
// each lane reads ONE uint4 (8 halves = 16B) per row -> full 256B row is one
// coalesced segment across the group. fp32 accumulate; 4x shfl_xor reduce.
// Error budget: fp16 storage err sigma ~0.0045 per dot, max ~0.023 << 0.0625
// tolerance. Falls back to pure-fp32 path if ws_size too small.

constexpr int D   = 128;
constexpr int LPE = 16;   // lanes per edge

// ---------- conversion: h (fp32) -> hh (fp16) ----------
__global__ __launch_bounds__(256) void convert_kernel(
    const float* __restrict__ h, __half* __restrict__ hh, int n4)
{
    const int stride = gridDim.x * blockDim.x;
    for (int k = blockIdx.x * blockDim.x + threadIdx.x; k < n4; k += stride) {
        float4 v = reinterpret_cast<const float4*>(h)[k];
        __half2 a = __floats2half2_rn(v.x, v.y);
        __half2 b = __floats2half2_rn(v.z, v.w);
        uint2 packed;
        packed.x = *reinterpret_cast<unsigned int*>(&a);
        packed.y = *reinterpret_cast<unsigned int*>(&b);
        reinterpret_cast<uint2*>(hh)[k] = packed;
    }
}

__device__ __forceinline__ float dot8(uint4 ua, uint4 ub)
{
    float acc = 0.f;
    const unsigned int* pa = &ua.x;
    const unsigned int* pb = &ub.x;
#pragma unroll
    for (int i = 0; i < 4; ++i) {
        __half2 ha = *reinterpret_cast<const __half2*>(&pa[i]);
        __half2 hb = *reinterpret_cast<const __half2*>(&pb[i]);
        float2 fa = __half22float2(ha);
        float2 fb = __half22float2(hb);
        acc = fmaf(fa.x, fb.x, acc);
        acc = fmaf(fa.y, fb.y, acc);
    }
    return acc;
}

// ---------- fp16 gather kernel ----------
__global__ __launch_bounds__(256) void edge_dot_f16_kernel(
    const __half* __restrict__ hh,
    const int*    __restrict__ src,
    const int*    __restrict__ dst,
    float*        __restrict__ out,
    int E)
{
    const int tid    = blockIdx.x * blockDim.x + threadIdx.x;
    const int sub    = threadIdx.x & (LPE - 1);
    const int slot   = tid / LPE;
    const int nslots = (gridDim.x * blockDim.x) / LPE;

    int e = slot;
    int s1 = 0, t1 = 0, s2 = 0, t2 = 0;
    if (e + nslots < E) {
        s1 = src[e];          t1 = dst[e];
        s2 = src[e + nslots]; t2 = dst[e + nslots];
    }

    while (e + nslots < E) {
        const int e2 = e + nslots;
        const int en = e + 2 * nslots;

        // One uint4 (8 halves) per lane per row; 4 independent loads in flight.
        const uint4* hu1 = reinterpret_cast<const uint4*>(hh + (size_t)s1 * D) + sub;
        const uint4* hv1 = reinterpret_cast<const uint4*>(hh + (size_t)t1 * D) + sub;
        const uint4* hu2 = reinterpret_cast<const uint4*>(hh + (size_t)s2 * D) + sub;
        const uint4* hv2 = reinterpret_cast<const uint4*>(hh + (size_t)t2 * D) + sub;

        uint4 a = *hu1;
        uint4 b = *hv1;
        uint4 c = *hu2;
        uint4 d = *hv2;

        // Prefetch next pair's indices while row loads are in flight.
        if (en + nslots < E) {
            s1 = src[en];          t1 = dst[en];
            s2 = src[en + nslots]; t2 = dst[en + nslots];
        }

        float acc1 = dot8(a, b);
        float acc2 = dot8(c, d);

        acc1 += __shfl_xor(acc1, 1);
        acc1 += __shfl_xor(acc1, 2);
        acc1 += __shfl_xor(acc1, 4);
        acc1 += __shfl_xor(acc1, 8);
        acc2 += __shfl_xor(acc2, 1);
        acc2 += __shfl_xor(acc2, 2);
        acc2 += __shfl_xor(acc2, 4);
        acc2 += __shfl_xor(acc2, 8);

        if (sub == 0) {
            out[e]  = acc1;
            out[e2] = acc2;
        }
        e = en;
    }
    if (e < E) {
        const int s = src[e];
        const int t = dst[e];
        uint4 a = *(reinterpret_cast<const uint4*>(hh + (size_t)s * D) + sub);
        uint4 b = *(reinterpret_cast<const uint4*>(hh + (size_t)t * D) + sub);
        float acc = dot8(a, b);
        acc += __shfl_xor(acc, 1);
        acc += __shfl_xor(acc, 2);
        acc += __shfl_xor(acc, 4);
        acc += __shfl_xor(acc, 8);
        if (sub == 0) out[e] = acc;
    }
}

// ---------- fp32 fallback (round-2 kernel) ----------
__global__ __launch_bounds__(256) void edge_dot_f32_kernel(
    const float* __restrict__ h,
    const int*   __restrict__ src,
    const int*   __restrict__ dst,
    float*       __restrict__ out,
    int E)
{
    const int tid    = blockIdx.x * blockDim.x + threadIdx.x;
    const int sub    = threadIdx.x & (LPE - 1);
    const int slot   = tid / LPE;
    const int nslots = (gridDim.x * blockDim.x) / LPE;
    const int off    = sub * 2;

    for (int e = slot; e < E; e += nslots) {
        const int s = src[e];
        const int t = dst[e];
        const float4* hu = reinterpret_cast<const float4*>(h + (size_t)s * D) + off;
        const float4* hv = reinterpret_cast<const float4*>(h + (size_t)t * D) + off;
        float4 a0 = hu[0]; float4 a1 = hu[1];
        float4 b0 = hv[0]; float4 b1 = hv[1];
        float acc = a0.x * b0.x + a0.y * b0.y + a0.z * b0.z + a0.w * b0.w
                  + a1.x * b1.x + a1.y * b1.y + a1.z * b1.z + a1.w * b1.w;
        acc += __shfl_xor(acc, 1);
        acc += __shfl_xor(acc, 2);
        acc += __shfl_xor(acc, 4);
        acc += __shfl_xor(acc, 8);
        if (sub == 0) out[e] = acc;
    }
}

extern "C" void kernel_launch(void* const* d_in, const int* in_sizes, int n_in,
                              void* d_out, int out_size, void* d_ws, size_t ws_size,
                              hipStream_t stream) {
    const float* h   = (const float*)d_in[0];
    const int*   src = (const int*)d_in[1];
    const int*   dst = (const int*)d_in[2];
    float*       out = (float*)d_out;

    const int hN = in_sizes[0];     // N*D floats
    const int E  = in_sizes[1];     // edges

    const int block = 256;
    int grid = (E + (block / LPE) - 1) / (block / LPE);
    if (grid > 2048) grid = 2048;

    const size_t need = (size_t)hN * sizeof(__half);
    if (ws_size >= need) {
        __half* hh = (__half*)d_ws;
        // convert h -> fp16 (must run every call: ws is re-poisoned)
        convert_kernel<<<2048, 256, 0, stream>>>(h, hh, hN / 4);
        edge_dot_f16_kernel<<<grid, block, 0, stream>>>(hh, src, dst, out, E);
    } else {
        edge_dot_f32_kernel<<<grid, block, 0, stream>>>(h, src, dst, out, E);
    }
}